// Round 8
// baseline (283.949 us; speedup 1.0000x reference)
//
#include <hip/hip_runtime.h>
#include <hip/hip_bf16.h>

// ---------------------------------------------------------------------------
// B=2, S=2048, D=768, H=12, Dh=64. M = B*S = 4096.
// R8: identical to R7 except attn_mfma gets __launch_bounds__(256,3).
// R7's TK=128 attn spilled (VGPR capped at 68 vs ~100 live regs ->
// WRITE_SIZE 329 MB of scratch). (256,3) = 3 blocks/CU target = what LDS
// (51 KB) and grid (768 blocks/256 CU) already allow -> VGPR budget ~170.
// ---------------------------------------------------------------------------

typedef __attribute__((ext_vector_type(8))) short short8;   // 8 x bf16 (4 VGPR)
typedef __attribute__((ext_vector_type(4))) float float4e;  // 4 x fp32 acc

__device__ __forceinline__ ushort f2bf(float f) {
    union { float f; unsigned u; } v; v.f = f;
    unsigned r = v.u + 0x7FFF + ((v.u >> 16) & 1);
    return (ushort)(r >> 16);
}

// ===========================================================================
// x [4096x768] fp32 -> bf16
// ===========================================================================
__global__ __launch_bounds__(256) void cast_f32_bf16(
    const float* __restrict__ in, ushort* __restrict__ out, int n4)
{
    int i = blockIdx.x * blockDim.x + threadIdx.x;
    if (i < n4) {
        float4 v = *(const float4*)&in[(size_t)i * 4];
        ushort4 o;
        o.x = f2bf(v.x); o.y = f2bf(v.y); o.z = f2bf(v.z); o.w = f2bf(v.w);
        *(ushort4*)&out[(size_t)i * 4] = o;
    }
}

// ===========================================================================
// All 4 weight transposes in one launch: z selects Wq/Wk/Wv/Wo.
// ===========================================================================
__global__ __launch_bounds__(256) void transpose_cast_w4(
    const float* __restrict__ W0, const float* __restrict__ W1,
    const float* __restrict__ W2, const float* __restrict__ W3,
    ushort* __restrict__ WtBase)
{
    __shared__ float t[64][65];
    const int z = blockIdx.z;
    const float* W = (z == 0) ? W0 : (z == 1) ? W1 : (z == 2) ? W2 : W3;
    ushort* Wt = WtBase + (size_t)z * (768u * 768u);

    const int tid = threadIdx.x;
    const int c  = tid & 63;
    const int rg = tid >> 6;
    const int k0 = blockIdx.y * 64, n0 = blockIdx.x * 64;
    #pragma unroll
    for (int r = 0; r < 16; ++r) {
        const int row = rg * 16 + r;
        t[row][c] = W[(size_t)(k0 + row) * 768 + n0 + c];
    }
    __syncthreads();
    #pragma unroll
    for (int r = 0; r < 16; ++r) {
        const int row = rg * 16 + r;
        Wt[(size_t)(n0 + row) * 768 + k0 + c] = f2bf(t[c][row]);
    }
}

// ===========================================================================
// V [4096x768] bf16 -> VT[b][h][d][s] bf16 (s-major per head).
// ===========================================================================
__global__ __launch_bounds__(256) void transpose_v(
    const ushort* __restrict__ Vb, ushort* __restrict__ VT)
{
    __shared__ ushort t[64][72];
    const int tid = threadIdx.x;
    const int b = blockIdx.z, h = blockIdx.y, s0 = blockIdx.x * 64;
    const int lr = tid >> 3;          // 0..31
    const int lc = (tid & 7) * 8;     // 0..56

    #pragma unroll
    for (int half = 0; half < 64; half += 32) {
        const int row = lr + half;
        *(uint4*)&t[row][lc] =
            *(const uint4*)&Vb[(size_t)(b * 2048 + s0 + row) * 768 + h * 64 + lc];
    }
    __syncthreads();
    #pragma unroll
    for (int half = 0; half < 64; half += 32) {
        const int d = lr + half;
        ushort tmp[8];
        #pragma unroll
        for (int i = 0; i < 8; ++i) tmp[i] = t[lc + i][d];
        *(uint4*)&VT[((size_t)(b * 12 + h) * 64 + d) * 2048 + s0 + lc] =
            *(const uint4*)tmp;
    }
}

// ===========================================================================
// Fused QKV GEMM: Out[M,2304] = x[M,768] @ [Wq|Wk|Wv]^T + [bq|bk|bv]
// 128x128 tile, BK=32, 4 waves 2x2, 16 accs/wave, register prefetch.
// ===========================================================================
__global__ __launch_bounds__(256) void gemm_qkv_fused(
    const ushort* __restrict__ A, const ushort* __restrict__ Bt,
    const float* __restrict__ bq, const float* __restrict__ bk,
    const float* __restrict__ bv, ushort* __restrict__ Outbase)
{
    constexpr int K = 768;
    __shared__ ushort As[128][40];
    __shared__ ushort Bs[128][40];

    const int tid  = threadIdx.x;
    const int w    = tid >> 6;
    const int lane = tid & 63;
    const int l16  = lane & 15;
    const int quad = lane >> 4;
    const int wr   = (w >> 1) * 64;
    const int wc   = (w & 1) * 64;
    const int row0 = blockIdx.y * 128, col0 = blockIdx.x * 128;
    const int sr = tid >> 2, sc = (tid & 3) * 8;

    float4e acc[4][4];
    #pragma unroll
    for (int mi = 0; mi < 4; ++mi)
        #pragma unroll
        for (int ni = 0; ni < 4; ++ni) acc[mi][ni] = (float4e){0.f,0.f,0.f,0.f};

    uint4 a0 = *(const uint4*)&A [(size_t)(row0 + sr     ) * K + sc];
    uint4 a1 = *(const uint4*)&A [(size_t)(row0 + sr + 64) * K + sc];
    uint4 b0 = *(const uint4*)&Bt[(size_t)(col0 + sr     ) * K + sc];
    uint4 b1 = *(const uint4*)&Bt[(size_t)(col0 + sr + 64) * K + sc];

    for (int k0 = 0; k0 < K; k0 += 32) {
        *(uint4*)&As[sr     ][sc] = a0;
        *(uint4*)&As[sr + 64][sc] = a1;
        *(uint4*)&Bs[sr     ][sc] = b0;
        *(uint4*)&Bs[sr + 64][sc] = b1;
        __syncthreads();

        if (k0 + 32 < K) {
            const int kn = k0 + 32;
            a0 = *(const uint4*)&A [(size_t)(row0 + sr     ) * K + kn + sc];
            a1 = *(const uint4*)&A [(size_t)(row0 + sr + 64) * K + kn + sc];
            b0 = *(const uint4*)&Bt[(size_t)(col0 + sr     ) * K + kn + sc];
            b1 = *(const uint4*)&Bt[(size_t)(col0 + sr + 64) * K + kn + sc];
        }

        short8 af[4], bf[4];
        #pragma unroll
        for (int i = 0; i < 4; ++i) {
            af[i] = *(const short8*)&As[wr + i * 16 + l16][quad * 8];
            bf[i] = *(const short8*)&Bs[wc + i * 16 + l16][quad * 8];
        }
        #pragma unroll
        for (int mi = 0; mi < 4; ++mi)
            #pragma unroll
            for (int ni = 0; ni < 4; ++ni)
                acc[mi][ni] = __builtin_amdgcn_mfma_f32_16x16x32_bf16(
                    af[mi], bf[ni], acc[mi][ni], 0, 0, 0);
        __syncthreads();
    }

    const int seg = (col0 >= 1536) ? 2 : (col0 >= 768 ? 1 : 0);
    const float* bias = (seg == 0) ? bq : (seg == 1) ? bk : bv;
    const int ncol0 = col0 - seg * 768 + wc;
    ushort* outp = Outbase + (size_t)seg * (4096u * 768u);

    #pragma unroll
    for (int ni = 0; ni < 4; ++ni) {
        const int col = ncol0 + ni * 16 + l16;
        const float bs = bias[col];
        #pragma unroll
        for (int mi = 0; mi < 4; ++mi) {
            #pragma unroll
            for (int r = 0; r < 4; ++r) {
                const int row = row0 + wr + mi * 16 + quad * 4 + r;
                outp[(size_t)row * 768 + col] = f2bf(acc[mi][ni][r] + bs);
            }
        }
    }
}

// ===========================================================================
// Wo GEMM: C[4096,768](fp32) = ctx[4096,768] @ Wo^T + bo. 128x128 tile.
// ===========================================================================
__global__ __launch_bounds__(256) void gemm_wo_128(
    const ushort* __restrict__ A, const ushort* __restrict__ Bt,
    const float* __restrict__ bias, float* __restrict__ Cout)
{
    constexpr int K = 768, N = 768;
    __shared__ ushort As[128][40];
    __shared__ ushort Bs[128][40];

    const int tid  = threadIdx.x;
    const int w    = tid >> 6;
    const int lane = tid & 63;
    const int l16  = lane & 15;
    const int quad = lane >> 4;
    const int wr   = (w >> 1) * 64;
    const int wc   = (w & 1) * 64;
    const int row0 = blockIdx.y * 128, col0 = blockIdx.x * 128;
    const int sr = tid >> 2, sc = (tid & 3) * 8;

    float4e acc[4][4];
    #pragma unroll
    for (int mi = 0; mi < 4; ++mi)
        #pragma unroll
        for (int ni = 0; ni < 4; ++ni) acc[mi][ni] = (float4e){0.f,0.f,0.f,0.f};

    uint4 a0 = *(const uint4*)&A [(size_t)(row0 + sr     ) * K + sc];
    uint4 a1 = *(const uint4*)&A [(size_t)(row0 + sr + 64) * K + sc];
    uint4 b0 = *(const uint4*)&Bt[(size_t)(col0 + sr     ) * K + sc];
    uint4 b1 = *(const uint4*)&Bt[(size_t)(col0 + sr + 64) * K + sc];

    for (int k0 = 0; k0 < K; k0 += 32) {
        *(uint4*)&As[sr     ][sc] = a0;
        *(uint4*)&As[sr + 64][sc] = a1;
        *(uint4*)&Bs[sr     ][sc] = b0;
        *(uint4*)&Bs[sr + 64][sc] = b1;
        __syncthreads();

        if (k0 + 32 < K) {
            const int kn = k0 + 32;
            a0 = *(const uint4*)&A [(size_t)(row0 + sr     ) * K + kn + sc];
            a1 = *(const uint4*)&A [(size_t)(row0 + sr + 64) * K + kn + sc];
            b0 = *(const uint4*)&Bt[(size_t)(col0 + sr     ) * K + kn + sc];
            b1 = *(const uint4*)&Bt[(size_t)(col0 + sr + 64) * K + kn + sc];
        }

        short8 af[4], bf[4];
        #pragma unroll
        for (int i = 0; i < 4; ++i) {
            af[i] = *(const short8*)&As[wr + i * 16 + l16][quad * 8];
            bf[i] = *(const short8*)&Bs[wc + i * 16 + l16][quad * 8];
        }
        #pragma unroll
        for (int mi = 0; mi < 4; ++mi)
            #pragma unroll
            for (int ni = 0; ni < 4; ++ni)
                acc[mi][ni] = __builtin_amdgcn_mfma_f32_16x16x32_bf16(
                    af[mi], bf[ni], acc[mi][ni], 0, 0, 0);
        __syncthreads();
    }

    #pragma unroll
    for (int ni = 0; ni < 4; ++ni) {
        const int col = col0 + wc + ni * 16 + l16;
        const float bs = bias[col];
        #pragma unroll
        for (int mi = 0; mi < 4; ++mi) {
            #pragma unroll
            for (int r = 0; r < 4; ++r) {
                const int row = row0 + wr + mi * 16 + quad * 4 + r;
                Cout[(size_t)row * N + col] = acc[mi][ni][r] + bs;
            }
        }
    }
}

// ===========================================================================
// Flash attention, S^T formulation, TK=128 keys/iteration (16 barriers).
// __launch_bounds__(256,3): 3 blocks/CU (= LDS & grid limit) -> VGPR
// budget ~170 covers the ~100-reg live set (sa[8]+kf/vf prefetch+oa+yq)
// WITHOUT scratch spill (R7: default heuristic gave 68 VGPR -> 329 MB
// scratch writes).
// ===========================================================================
__global__ __launch_bounds__(256, 3) void attn_mfma(
    const ushort* __restrict__ Qg, const ushort* __restrict__ Kgl,
    const ushort* __restrict__ VT, ushort* __restrict__ Ctx)
{
    constexpr int S = 2048, D = 768, TK = 128;
    __shared__ ushort Ks [128][68];   // [key][d]   rows 136B
    __shared__ ushort Vts[64][136];   // [d][key]   rows 272B
    __shared__ ushort Ps [64][136];   // [w*16+query][key]

    const int tid  = threadIdx.x;
    const int w    = tid >> 6;
    const int lane = tid & 63;
    const int l16  = lane & 15;
    const int quad = lane >> 4;
    const int b = blockIdx.z, h = blockIdx.y, q0 = blockIdx.x * 64;
    const size_t hc = (size_t)h * 64;

    const size_t qoff = (size_t)(b * S + q0 + w * 16 + l16) * D + hc + quad * 8;
    const short8 yq0 = *(const short8*)&Qg[qoff];
    const short8 yq1 = *(const short8*)&Qg[qoff + 32];

    float m_ = -1e30f, l_ = 0.f;
    float4e oa[4];
    #pragma unroll
    for (int n = 0; n < 4; ++n) oa[n] = (float4e){0.f, 0.f, 0.f, 0.f};

    // staging: K 128x64 -> kr=tid>>1, kc=(tid&1)*32 (4 uint4);
    //          V  64x128 -> dr=tid>>2, vc=(tid&3)*32 (4 uint4)
    const int kr = tid >> 1, kc = (tid & 1) * 32;
    const int dr = tid >> 2, vc = (tid & 3) * 32;
    const size_t vtb = ((size_t)(b * 12 + h) * 64 + dr) * 2048;

    uint4 kf[4], vf[4];
    #pragma unroll
    for (int j = 0; j < 4; ++j) {
        kf[j] = *(const uint4*)&Kgl[(size_t)(b * S + kr) * D + hc + kc + 8 * j];
        vf[j] = *(const uint4*)&VT[vtb + vc + 8 * j];
    }

    for (int k0 = 0; k0 < S; k0 += TK) {
        #pragma unroll
        for (int j = 0; j < 4; ++j) {
            *(uint4*)&Ks [kr][kc + 8 * j] = kf[j];
            *(uint4*)&Vts[dr][vc + 8 * j] = vf[j];
        }
        __syncthreads();

        if (k0 + TK < S) {
            #pragma unroll
            for (int j = 0; j < 4; ++j) {
                kf[j] = *(const uint4*)&Kgl[(size_t)(b * S + k0 + TK + kr) * D + hc + kc + 8 * j];
                vf[j] = *(const uint4*)&VT[vtb + k0 + TK + vc + 8 * j];
            }
        }

        // ---- scores for 128 keys ----
        float4e sa[8];
        #pragma unroll
        for (int kb = 0; kb < 8; ++kb) {
            const short8 xk0 = *(const short8*)&Ks[kb * 16 + l16][quad * 8];
            const short8 xk1 = *(const short8*)&Ks[kb * 16 + l16][32 + quad * 8];
            float4e z = (float4e){0.f, 0.f, 0.f, 0.f};
            z      = __builtin_amdgcn_mfma_f32_16x16x32_bf16(xk0, yq0, z, 0, 0, 0);
            sa[kb] = __builtin_amdgcn_mfma_f32_16x16x32_bf16(xk1, yq1, z, 0, 0, 0);
        }

        // ---- online softmax over 32 in-lane values + 2 shuffles ----
        float mx = -1e30f;
        #pragma unroll
        for (int kb = 0; kb < 8; ++kb)
            #pragma unroll
            for (int r = 0; r < 4; ++r) mx = fmaxf(mx, sa[kb][r]);
        mx = fmaxf(mx, __shfl_xor(mx, 16, 64));
        mx = fmaxf(mx, __shfl_xor(mx, 32, 64));
        const float mn = fmaxf(m_, mx);
        const float alpha = __expf(m_ - mn);    // first iter: 0
        float ps = 0.f;
        #pragma unroll
        for (int kb = 0; kb < 8; ++kb) {
            float p0 = __expf(sa[kb][0] - mn);
            float p1 = __expf(sa[kb][1] - mn);
            float p2 = __expf(sa[kb][2] - mn);
            float p3 = __expf(sa[kb][3] - mn);
            ps += (p0 + p1) + (p2 + p3);
            ushort4 pk;
            pk.x = f2bf(p0); pk.y = f2bf(p1); pk.z = f2bf(p2); pk.w = f2bf(p3);
            *(ushort4*)&Ps[w * 16 + l16][kb * 16 + quad * 4] = pk;
        }
        ps += __shfl_xor(ps, 16, 64);
        ps += __shfl_xor(ps, 32, 64);
        l_ = l_ * alpha + ps;
        m_ = mn;

        // ---- rescale O^T, accumulate PV over 4 key-chains of 32 ----
        #pragma unroll
        for (int n = 0; n < 4; ++n)
            #pragma unroll
            for (int r = 0; r < 4; ++r) oa[n][r] *= alpha;

        #pragma unroll
        for (int c = 0; c < 4; ++c) {
            const short8 yp = *(const short8*)&Ps[w * 16 + l16][c * 32 + quad * 8];
            #pragma unroll
            for (int db = 0; db < 4; ++db) {
                const short8 xv = *(const short8*)&Vts[db * 16 + l16][c * 32 + quad * 8];
                oa[db] = __builtin_amdgcn_mfma_f32_16x16x32_bf16(xv, yp, oa[db], 0, 0, 0);
            }
        }
        __syncthreads();
    }

    // ---- normalize, write ctx: lane owns query l16, dims db*16+quad*4+r ----
    const float inv = 1.0f / l_;
    const size_t crow = (size_t)(b * S + q0 + w * 16 + l16) * D + hc;
    #pragma unroll
    for (int db = 0; db < 4; ++db) {
        ushort4 ov;
        ov.x = f2bf(oa[db][0] * inv); ov.y = f2bf(oa[db][1] * inv);
        ov.z = f2bf(oa[db][2] * inv); ov.w = f2bf(oa[db][3] * inv);
        *(ushort4*)&Ctx[crow + db * 16 + quad * 4] = ov;
    }
}

// ===========================================================================
// Launch
// ===========================================================================
extern "C" void kernel_launch(void* const* d_in, const int* in_sizes, int n_in,
                              void* d_out, int out_size, void* d_ws, size_t ws_size,
                              hipStream_t stream)
{
    const float* x  = (const float*)d_in[0];
    const float* Wq = (const float*)d_in[1];
    const float* bq = (const float*)d_in[2];
    const float* Wk = (const float*)d_in[3];
    const float* bk = (const float*)d_in[4];
    const float* Wv = (const float*)d_in[5];
    const float* bv = (const float*)d_in[6];
    const float* Wo = (const float*)d_in[7];
    const float* bo = (const float*)d_in[8];

    const int M = 4096, D = 768;
    const size_t XE = (size_t)M * D;     // 3,145,728
    const size_t WE = (size_t)D * D;     //   589,824

    ushort* xb   = (ushort*)d_ws;
    ushort* wtq  = xb   + XE;            // wtq/wtk/wtv/wto contiguous
    ushort* wto  = wtq  + 3 * WE;
    ushort* qb   = wto  + WE;            // qb/kb/vb contiguous
    ushort* kb   = qb   + XE;
    ushort* vb   = kb   + XE;
    ushort* ctxb = vb   + XE;
    ushort* vt   = xb;                   // reuse xb (dead after fused GEMM)

    cast_f32_bf16<<<(int)(XE / 4 / 256), 256, 0, stream>>>(x, xb, (int)(XE / 4));

    transpose_cast_w4<<<dim3(12, 12, 4), 256, 0, stream>>>(Wq, Wk, Wv, Wo, wtq);

    gemm_qkv_fused<<<dim3(2304 / 128, 4096 / 128), 256, 0, stream>>>(
        xb, wtq, bq, bk, bv, qb);

    transpose_v<<<dim3(32, 12, 2), 256, 0, stream>>>(vb, vt);

    attn_mfma<<<dim3(2048 / 64, 12, 2), 256, 0, stream>>>(qb, kb, vt, ctxb);

    gemm_wo_128<<<dim3(768 / 128, 4096 / 128), 256, 0, stream>>>(
        ctxb, wto, bo, (float*)d_out);
}

// Round 9
// 194.677 us; speedup vs baseline: 1.4586x; 1.4586x over previous
//
#include <hip/hip_runtime.h>
#include <hip/hip_bf16.h>

// ---------------------------------------------------------------------------
// B=2, S=2048, D=768, H=12, Dh=64. M = B*S = 4096.
// R9: attn reverted to R6 TK=64 (R7/R8 TK=128 spilled ~300 MB scratch,
// launch_bounds didn't move the allocator -> reverted per discipline).
// QKV GEMM staging rewritten to m97-style global_load_lds width=16
// (unpadded LDS, wave-uniform base + lane*16). Keep w4-fused transpose
// and 128-tile Wo GEMM from R7.
// ---------------------------------------------------------------------------

typedef __attribute__((ext_vector_type(8))) short short8;   // 8 x bf16 (4 VGPR)
typedef __attribute__((ext_vector_type(4))) float float4e;  // 4 x fp32 acc

__device__ __forceinline__ ushort f2bf(float f) {
    union { float f; unsigned u; } v; v.f = f;
    unsigned r = v.u + 0x7FFF + ((v.u >> 16) & 1);
    return (ushort)(r >> 16);
}

// async 16B global -> LDS (gfx950 global_load_lds_dwordx4).
// LDS dest = wave-uniform base + lane*16 (no per-lane scatter!).
__device__ __forceinline__ void async_cp16(const ushort* g, ushort* l) {
    __builtin_amdgcn_global_load_lds(
        (const __attribute__((address_space(1))) unsigned int*)g,
        (__attribute__((address_space(3))) unsigned int*)l,
        16, 0, 0);
}

// ===========================================================================
// x [4096x768] fp32 -> bf16
// ===========================================================================
__global__ __launch_bounds__(256) void cast_f32_bf16(
    const float* __restrict__ in, ushort* __restrict__ out, int n4)
{
    int i = blockIdx.x * blockDim.x + threadIdx.x;
    if (i < n4) {
        float4 v = *(const float4*)&in[(size_t)i * 4];
        ushort4 o;
        o.x = f2bf(v.x); o.y = f2bf(v.y); o.z = f2bf(v.z); o.w = f2bf(v.w);
        *(ushort4*)&out[(size_t)i * 4] = o;
    }
}

// ===========================================================================
// All 4 weight transposes in one launch: z selects Wq/Wk/Wv/Wo.
// ===========================================================================
__global__ __launch_bounds__(256) void transpose_cast_w4(
    const float* __restrict__ W0, const float* __restrict__ W1,
    const float* __restrict__ W2, const float* __restrict__ W3,
    ushort* __restrict__ WtBase)
{
    __shared__ float t[64][65];
    const int z = blockIdx.z;
    const float* W = (z == 0) ? W0 : (z == 1) ? W1 : (z == 2) ? W2 : W3;
    ushort* Wt = WtBase + (size_t)z * (768u * 768u);

    const int tid = threadIdx.x;
    const int c  = tid & 63;
    const int rg = tid >> 6;
    const int k0 = blockIdx.y * 64, n0 = blockIdx.x * 64;
    #pragma unroll
    for (int r = 0; r < 16; ++r) {
        const int row = rg * 16 + r;
        t[row][c] = W[(size_t)(k0 + row) * 768 + n0 + c];
    }
    __syncthreads();
    #pragma unroll
    for (int r = 0; r < 16; ++r) {
        const int row = rg * 16 + r;
        Wt[(size_t)(n0 + row) * 768 + k0 + c] = f2bf(t[c][row]);
    }
}

// ===========================================================================
// V [4096x768] bf16 -> VT[b][h][d][s] bf16 (s-major per head).
// ===========================================================================
__global__ __launch_bounds__(256) void transpose_v(
    const ushort* __restrict__ Vb, ushort* __restrict__ VT)
{
    __shared__ ushort t[64][72];
    const int tid = threadIdx.x;
    const int b = blockIdx.z, h = blockIdx.y, s0 = blockIdx.x * 64;
    const int lr = tid >> 3;          // 0..31
    const int lc = (tid & 7) * 8;     // 0..56

    #pragma unroll
    for (int half = 0; half < 64; half += 32) {
        const int row = lr + half;
        *(uint4*)&t[row][lc] =
            *(const uint4*)&Vb[(size_t)(b * 2048 + s0 + row) * 768 + h * 64 + lc];
    }
    __syncthreads();
    #pragma unroll
    for (int half = 0; half < 64; half += 32) {
        const int d = lr + half;
        ushort tmp[8];
        #pragma unroll
        for (int i = 0; i < 8; ++i) tmp[i] = t[lc + i][d];
        *(uint4*)&VT[((size_t)(b * 12 + h) * 64 + d) * 2048 + s0 + lc] =
            *(const uint4*)tmp;
    }
}

// ===========================================================================
// Fused QKV GEMM: Out[M,2304] = x[M,768] @ [Wq|Wk|Wv]^T + [bq|bk|bv]
// 128x128 tile, BK=32, 4 waves 2x2, 16 accs/wave.
// Staging via global_load_lds width=16 (m97): UNPADDED As/Bs[128][32],
// wave w covers rows [32w,32w+32) of each tile with 2 async issues
// (64 lanes x 16 B = 16 rows x 64 B per issue); lane l -> row +l>>2,
// col (l&3)*8. 2-barrier K-loop; barrier drains vmcnt (m97 semantics).
// ===========================================================================
__global__ __launch_bounds__(256) void gemm_qkv_fused(
    const ushort* __restrict__ A, const ushort* __restrict__ Bt,
    const float* __restrict__ bq, const float* __restrict__ bk,
    const float* __restrict__ bv, ushort* __restrict__ Outbase)
{
    constexpr int K = 768;
    __shared__ ushort As[128][32];   // unpadded: required by global_load_lds
    __shared__ ushort Bs[128][32];

    const int tid  = threadIdx.x;
    const int w    = tid >> 6;
    const int lane = tid & 63;
    const int l16  = lane & 15;
    const int quad = lane >> 4;
    const int wr   = (w >> 1) * 64;
    const int wc   = (w & 1) * 64;
    const int row0 = blockIdx.y * 128, col0 = blockIdx.x * 128;

    // staging mapping (per wave): rows w*32 + i*16 + (lane>>2), col (lane&3)*8
    const int r4 = lane >> 2;
    const int c8 = (lane & 3) * 8;

    float4e acc[4][4];
    #pragma unroll
    for (int mi = 0; mi < 4; ++mi)
        #pragma unroll
        for (int ni = 0; ni < 4; ++ni) acc[mi][ni] = (float4e){0.f,0.f,0.f,0.f};

    for (int k0 = 0; k0 < K; k0 += 32) {
        #pragma unroll
        for (int i = 0; i < 2; ++i) {
            const int rr = w * 32 + i * 16;
            async_cp16(&A [(size_t)(row0 + rr + r4) * K + k0 + c8], &As[rr][0]);
            async_cp16(&Bt[(size_t)(col0 + rr + r4) * K + k0 + c8], &Bs[rr][0]);
        }
        __syncthreads();   // drains vmcnt -> staged data visible

        short8 af[4], bf[4];
        #pragma unroll
        for (int i = 0; i < 4; ++i) {
            af[i] = *(const short8*)&As[wr + i * 16 + l16][quad * 8];
            bf[i] = *(const short8*)&Bs[wc + i * 16 + l16][quad * 8];
        }
        #pragma unroll
        for (int mi = 0; mi < 4; ++mi)
            #pragma unroll
            for (int ni = 0; ni < 4; ++ni)
                acc[mi][ni] = __builtin_amdgcn_mfma_f32_16x16x32_bf16(
                    af[mi], bf[ni], acc[mi][ni], 0, 0, 0);
        __syncthreads();
    }

    const int seg = (col0 >= 1536) ? 2 : (col0 >= 768 ? 1 : 0);
    const float* bias = (seg == 0) ? bq : (seg == 1) ? bk : bv;
    const int ncol0 = col0 - seg * 768 + wc;
    ushort* outp = Outbase + (size_t)seg * (4096u * 768u);

    #pragma unroll
    for (int ni = 0; ni < 4; ++ni) {
        const int col = ncol0 + ni * 16 + l16;
        const float bs = bias[col];
        #pragma unroll
        for (int mi = 0; mi < 4; ++mi) {
            #pragma unroll
            for (int r = 0; r < 4; ++r) {
                const int row = row0 + wr + mi * 16 + quad * 4 + r;
                outp[(size_t)row * 768 + col] = f2bf(acc[mi][ni][r] + bs);
            }
        }
    }
}

// ===========================================================================
// Wo GEMM: C[4096,768](fp32) = ctx[4096,768] @ Wo^T + bo. 128x128 tile,
// register-prefetch staging (unchanged from R7 - it worked).
// ===========================================================================
__global__ __launch_bounds__(256) void gemm_wo_128(
    const ushort* __restrict__ A, const ushort* __restrict__ Bt,
    const float* __restrict__ bias, float* __restrict__ Cout)
{
    constexpr int K = 768, N = 768;
    __shared__ ushort As[128][40];
    __shared__ ushort Bs[128][40];

    const int tid  = threadIdx.x;
    const int w    = tid >> 6;
    const int lane = tid & 63;
    const int l16  = lane & 15;
    const int quad = lane >> 4;
    const int wr   = (w >> 1) * 64;
    const int wc   = (w & 1) * 64;
    const int row0 = blockIdx.y * 128, col0 = blockIdx.x * 128;
    const int sr = tid >> 2, sc = (tid & 3) * 8;

    float4e acc[4][4];
    #pragma unroll
    for (int mi = 0; mi < 4; ++mi)
        #pragma unroll
        for (int ni = 0; ni < 4; ++ni) acc[mi][ni] = (float4e){0.f,0.f,0.f,0.f};

    uint4 a0 = *(const uint4*)&A [(size_t)(row0 + sr     ) * K + sc];
    uint4 a1 = *(const uint4*)&A [(size_t)(row0 + sr + 64) * K + sc];
    uint4 b0 = *(const uint4*)&Bt[(size_t)(col0 + sr     ) * K + sc];
    uint4 b1 = *(const uint4*)&Bt[(size_t)(col0 + sr + 64) * K + sc];

    for (int k0 = 0; k0 < K; k0 += 32) {
        *(uint4*)&As[sr     ][sc] = a0;
        *(uint4*)&As[sr + 64][sc] = a1;
        *(uint4*)&Bs[sr     ][sc] = b0;
        *(uint4*)&Bs[sr + 64][sc] = b1;
        __syncthreads();

        if (k0 + 32 < K) {
            const int kn = k0 + 32;
            a0 = *(const uint4*)&A [(size_t)(row0 + sr     ) * K + kn + sc];
            a1 = *(const uint4*)&A [(size_t)(row0 + sr + 64) * K + kn + sc];
            b0 = *(const uint4*)&Bt[(size_t)(col0 + sr     ) * K + kn + sc];
            b1 = *(const uint4*)&Bt[(size_t)(col0 + sr + 64) * K + kn + sc];
        }

        short8 af[4], bf[4];
        #pragma unroll
        for (int i = 0; i < 4; ++i) {
            af[i] = *(const short8*)&As[wr + i * 16 + l16][quad * 8];
            bf[i] = *(const short8*)&Bs[wc + i * 16 + l16][quad * 8];
        }
        #pragma unroll
        for (int mi = 0; mi < 4; ++mi)
            #pragma unroll
            for (int ni = 0; ni < 4; ++ni)
                acc[mi][ni] = __builtin_amdgcn_mfma_f32_16x16x32_bf16(
                    af[mi], bf[ni], acc[mi][ni], 0, 0, 0);
        __syncthreads();
    }

    #pragma unroll
    for (int ni = 0; ni < 4; ++ni) {
        const int col = col0 + wc + ni * 16 + l16;
        const float bs = bias[col];
        #pragma unroll
        for (int mi = 0; mi < 4; ++mi) {
            #pragma unroll
            for (int r = 0; r < 4; ++r) {
                const int row = row0 + wr + mi * 16 + quad * 4 + r;
                Cout[(size_t)row * N + col] = acc[mi][ni][r] + bs;
            }
        }
    }
}

// ===========================================================================
// Flash attention, S^T formulation, TK=64 (R6 verbatim: 69.5 us, VGPR 52,
// no spill). Block = (b, h, 64 queries); wave w owns queries [16w,16w+16).
//   scores: D[key][query] = mfma(K-frag, Q-frag); lane: query=l16,
//           keys kb*16+quad*4+r. Softmax: in-lane + shfl_xor(16,32).
//   P: 4 conflict-free b64 stores; PV: mfma(VT-frag, P-frag) -> O^T.
// ===========================================================================
__global__ __launch_bounds__(256) void attn_mfma(
    const ushort* __restrict__ Qg, const ushort* __restrict__ Kgl,
    const ushort* __restrict__ VT, ushort* __restrict__ Ctx)
{
    constexpr int S = 2048, D = 768;
    __shared__ ushort Ks [64][72];   // [key][d]
    __shared__ ushort Vts[64][72];   // [d][key]
    __shared__ ushort Ps [64][72];   // [w*16+query][key]

    const int tid  = threadIdx.x;
    const int w    = tid >> 6;
    const int lane = tid & 63;
    const int l16  = lane & 15;
    const int quad = lane >> 4;
    const int b = blockIdx.z, h = blockIdx.y, q0 = blockIdx.x * 64;
    const size_t hc = (size_t)h * 64;

    const size_t qoff = (size_t)(b * S + q0 + w * 16 + l16) * D + hc + quad * 8;
    const short8 yq0 = *(const short8*)&Qg[qoff];
    const short8 yq1 = *(const short8*)&Qg[qoff + 32];

    float m_ = -1e30f, l_ = 0.f;
    float4e oa[4];
    #pragma unroll
    for (int n = 0; n < 4; ++n) oa[n] = (float4e){0.f, 0.f, 0.f, 0.f};

    const int sr = tid >> 2;          // key row (Ks) / head-dim (Vts)
    const int sc = (tid & 3) * 16;
    const size_t vtb = ((size_t)(b * 12 + h) * 64 + sr) * 2048;

    uint4 kA, kB, vA, vB;
    {
        const size_t gk = (size_t)(b * S + sr) * D + hc + sc;
        kA = *(const uint4*)&Kgl[gk];
        kB = *(const uint4*)&Kgl[gk + 8];
        vA = *(const uint4*)&VT[vtb + sc];
        vB = *(const uint4*)&VT[vtb + sc + 8];
    }

    for (int k0 = 0; k0 < S; k0 += 64) {
        *(uint4*)&Ks [sr][sc    ] = kA;
        *(uint4*)&Ks [sr][sc + 8] = kB;
        *(uint4*)&Vts[sr][sc    ] = vA;
        *(uint4*)&Vts[sr][sc + 8] = vB;
        __syncthreads();

        if (k0 + 64 < S) {
            const size_t gk = (size_t)(b * S + k0 + 64 + sr) * D + hc + sc;
            kA = *(const uint4*)&Kgl[gk];
            kB = *(const uint4*)&Kgl[gk + 8];
            vA = *(const uint4*)&VT[vtb + k0 + 64 + sc];
            vB = *(const uint4*)&VT[vtb + k0 + 64 + sc + 8];
        }

        // ---- S^T: lane gets S[query=l16][key=kb*16+quad*4+r] ----
        float4e sa[4];
        #pragma unroll
        for (int kb = 0; kb < 4; ++kb) {
            const short8 xk0 = *(const short8*)&Ks[kb * 16 + l16][quad * 8];
            const short8 xk1 = *(const short8*)&Ks[kb * 16 + l16][32 + quad * 8];
            float4e z = (float4e){0.f, 0.f, 0.f, 0.f};
            z      = __builtin_amdgcn_mfma_f32_16x16x32_bf16(xk0, yq0, z, 0, 0, 0);
            sa[kb] = __builtin_amdgcn_mfma_f32_16x16x32_bf16(xk1, yq1, z, 0, 0, 0);
        }

        // ---- online softmax: 16 vals in-lane + 2 cross-quad shuffles ----
        float mx = -1e30f;
        #pragma unroll
        for (int kb = 0; kb < 4; ++kb)
            #pragma unroll
            for (int r = 0; r < 4; ++r) mx = fmaxf(mx, sa[kb][r]);
        mx = fmaxf(mx, __shfl_xor(mx, 16, 64));
        mx = fmaxf(mx, __shfl_xor(mx, 32, 64));
        const float mn = fmaxf(m_, mx);
        const float alpha = __expf(m_ - mn);    // first iter: 0
        float p[4][4], ps = 0.f;
        #pragma unroll
        for (int kb = 0; kb < 4; ++kb)
            #pragma unroll
            for (int r = 0; r < 4; ++r) {
                p[kb][r] = __expf(sa[kb][r] - mn);
                ps += p[kb][r];
            }
        ps += __shfl_xor(ps, 16, 64);
        ps += __shfl_xor(ps, 32, 64);
        l_ = l_ * alpha + ps;
        m_ = mn;

        // ---- P -> LDS: 4 contiguous keys per b64 write, conflict-free ----
        #pragma unroll
        for (int kb = 0; kb < 4; ++kb) {
            ushort4 pk;
            pk.x = f2bf(p[kb][0]); pk.y = f2bf(p[kb][1]);
            pk.z = f2bf(p[kb][2]); pk.w = f2bf(p[kb][3]);
            *(ushort4*)&Ps[w * 16 + l16][kb * 16 + quad * 4] = pk;
        }

        // ---- rescale O^T and accumulate PV ----
        #pragma unroll
        for (int n = 0; n < 4; ++n)
            #pragma unroll
            for (int r = 0; r < 4; ++r) oa[n][r] *= alpha;

        const short8 yp0 = *(const short8*)&Ps[w * 16 + l16][quad * 8];
        const short8 yp1 = *(const short8*)&Ps[w * 16 + l16][32 + quad * 8];
        #pragma unroll
        for (int db = 0; db < 4; ++db) {
            const short8 xv0 = *(const short8*)&Vts[db * 16 + l16][quad * 8];
            const short8 xv1 = *(const short8*)&Vts[db * 16 + l16][32 + quad * 8];
            oa[db] = __builtin_amdgcn_mfma_f32_16x16x32_bf16(xv0, yp0, oa[db], 0, 0, 0);
            oa[db] = __builtin_amdgcn_mfma_f32_16x16x32_bf16(xv1, yp1, oa[db], 0, 0, 0);
        }
        __syncthreads();
    }

    // ---- normalize, write ctx: lane owns query l16, dims db*16+quad*4+r ----
    const float inv = 1.0f / l_;
    const size_t crow = (size_t)(b * S + q0 + w * 16 + l16) * D + hc;
    #pragma unroll
    for (int db = 0; db < 4; ++db) {
        ushort4 ov;
        ov.x = f2bf(oa[db][0] * inv); ov.y = f2bf(oa[db][1] * inv);
        ov.z = f2bf(oa[db][2] * inv); ov.w = f2bf(oa[db][3] * inv);
        *(ushort4*)&Ctx[crow + db * 16 + quad * 4] = ov;
    }
}

// ===========================================================================
// Launch
// ===========================================================================
extern "C" void kernel_launch(void* const* d_in, const int* in_sizes, int n_in,
                              void* d_out, int out_size, void* d_ws, size_t ws_size,
                              hipStream_t stream)
{
    const float* x  = (const float*)d_in[0];
    const float* Wq = (const float*)d_in[1];
    const float* bq = (const float*)d_in[2];
    const float* Wk = (const float*)d_in[3];
    const float* bk = (const float*)d_in[4];
    const float* Wv = (const float*)d_in[5];
    const float* bv = (const float*)d_in[6];
    const float* Wo = (const float*)d_in[7];
    const float* bo = (const float*)d_in[8];

    const int M = 4096, D = 768;
    const size_t XE = (size_t)M * D;     // 3,145,728
    const size_t WE = (size_t)D * D;     //   589,824

    ushort* xb   = (ushort*)d_ws;
    ushort* wtq  = xb   + XE;            // wtq/wtk/wtv/wto contiguous
    ushort* wto  = wtq  + 3 * WE;
    ushort* qb   = wto  + WE;            // qb/kb/vb contiguous
    ushort* kb   = qb   + XE;
    ushort* vb   = kb   + XE;
    ushort* ctxb = vb   + XE;
    ushort* vt   = xb;                   // reuse xb (dead after fused GEMM)

    cast_f32_bf16<<<(int)(XE / 4 / 256), 256, 0, stream>>>(x, xb, (int)(XE / 4));

    transpose_cast_w4<<<dim3(12, 12, 4), 256, 0, stream>>>(Wq, Wk, Wv, Wo, wtq);

    gemm_qkv_fused<<<dim3(2304 / 128, 4096 / 128), 256, 0, stream>>>(
        xb, wtq, bq, bk, bv, qb);

    transpose_v<<<dim3(32, 12, 2), 256, 0, stream>>>(vb, vt);

    attn_mfma<<<dim3(2048 / 64, 12, 2), 256, 0, stream>>>(qb, kb, vt, ctxb);

    gemm_wo_128<<<dim3(768 / 128, 4096 / 128), 256, 0, stream>>>(
        ctxb, wto, bo, (float*)d_out);
}